// Round 3
// baseline (2588.369 us; speedup 1.0000x reference)
//
#include <hip/hip_runtime.h>
#include <cmath>

// Problem constants
static constexpr int NB   = 128;   // batch
static constexpr int NT   = 512;   // time
static constexpr int ND   = 128;   // embed dim
static constexpr int NH   = 128;   // hidden per direction
static constexpr int NG4  = 512;   // 4*H
static constexpr int NKT  = 32;    // num tags
static constexpr int CHUNK = 128;  // timesteps per chunk
static constexpr int NCH  = NT / CHUNK;

__device__ __forceinline__ float sigf(float x) { return 1.0f / (1.0f + expf(-x)); }

// ---------------------------------------------------------------------------
// Projection GEMM: zin[d][b][s][j] = bias[d][j] + sum_k Wih[d][j][k] * X(b,t(d,c,s),k)
// Block tile: 128 rows (s) x 256 cols (j), 256 threads, 8x16 acc per thread.
// NOTE: no min-waves clamp — needs ~200 VGPR; (256,2) caused scratch spill.
// ---------------------------------------------------------------------------
template <int DIN>
__global__ __launch_bounds__(256) void proj_gemm(
    const float* __restrict__ Wih,    // [2][512][DIN]
    const float* __restrict__ bias,   // [2][512]
    const float* __restrict__ xsrc,   // emb [V][128] (l0) or h1 [B][T][256] (l1)
    const int*   __restrict__ inputs, // [B][T] (l0 only)
    float*       __restrict__ zin,    // [2][B][CHUNK][512]
    int c)
{
    constexpr int KT = DIN / 16;  // K-steps
    __shared__ __align__(16) float A[16][128];
    __shared__ __align__(16) float Bs[16][256];
    __shared__ const float* rowp[128];

    const int bid = blockIdx.x;
    const int d  = bid >> 8;
    const int b  = (bid >> 1) & 127;
    const int ct = bid & 1;
    const int tid = threadIdx.x;
    const int tx = tid & 15;   // col group: cols ct*256 + g*64 + tx*4, g=0..3
    const int ty = tid >> 4;   // row group: rows ty*8 .. ty*8+7
    const int rr = tid & 127;  // staging row
    const int kh = tid >> 7;   // staging k-half (0/1)

    // Per-row source pointers (gather for layer0).
    if (tid < 128) {
        const int s = tid;
        const int ttl = c * CHUNK + s;
        const int t = d ? (NT - 1 - ttl) : ttl;
        if constexpr (DIN == 128) {
            rowp[tid] = xsrc + (size_t)inputs[b * NT + t] * ND;
        } else {
            rowp[tid] = xsrc + ((size_t)(b * NT + t)) * 256;
        }
    }
    __syncthreads();

    const float* myrow = rowp[rr];                                  // A staging src
    const float* wrow  = Wih + ((size_t)(d * NG4 + ct * 256 + tid)) * DIN;  // B staging src

    float acc[8][16];
#pragma unroll
    for (int i = 0; i < 8; ++i)
#pragma unroll
        for (int n = 0; n < 16; ++n) acc[i][n] = 0.0f;

    // Prefetch kt=0 into registers.
    float4 pa0 = *(const float4*)(myrow + kh * 8);
    float4 pa1 = *(const float4*)(myrow + kh * 8 + 4);
    float4 pb0 = *(const float4*)(wrow + 0);
    float4 pb1 = *(const float4*)(wrow + 4);
    float4 pb2 = *(const float4*)(wrow + 8);
    float4 pb3 = *(const float4*)(wrow + 12);

    for (int kt = 0; kt < KT; ++kt) {
        __syncthreads();  // previous compute done; LDS safe to overwrite
        // Stage A: A[k][rr], k = kh*8 .. kh*8+7
        A[kh * 8 + 0][rr] = pa0.x; A[kh * 8 + 1][rr] = pa0.y;
        A[kh * 8 + 2][rr] = pa0.z; A[kh * 8 + 3][rr] = pa0.w;
        A[kh * 8 + 4][rr] = pa1.x; A[kh * 8 + 5][rr] = pa1.y;
        A[kh * 8 + 6][rr] = pa1.z; A[kh * 8 + 7][rr] = pa1.w;
        // Stage B transposed: Bs[k][tid], k = 0..15
        Bs[ 0][tid] = pb0.x; Bs[ 1][tid] = pb0.y; Bs[ 2][tid] = pb0.z; Bs[ 3][tid] = pb0.w;
        Bs[ 4][tid] = pb1.x; Bs[ 5][tid] = pb1.y; Bs[ 6][tid] = pb1.z; Bs[ 7][tid] = pb1.w;
        Bs[ 8][tid] = pb2.x; Bs[ 9][tid] = pb2.y; Bs[10][tid] = pb2.z; Bs[11][tid] = pb2.w;
        Bs[12][tid] = pb3.x; Bs[13][tid] = pb3.y; Bs[14][tid] = pb3.z; Bs[15][tid] = pb3.w;
        __syncthreads();

        // Prefetch next kt while computing this one.
        if (kt + 1 < KT) {
            const int k0 = (kt + 1) * 16;
            pa0 = *(const float4*)(myrow + k0 + kh * 8);
            pa1 = *(const float4*)(myrow + k0 + kh * 8 + 4);
            pb0 = *(const float4*)(wrow + k0 + 0);
            pb1 = *(const float4*)(wrow + k0 + 4);
            pb2 = *(const float4*)(wrow + k0 + 8);
            pb3 = *(const float4*)(wrow + k0 + 12);
        }

#pragma unroll 4
        for (int k = 0; k < 16; ++k) {
            float4 a0 = *(const float4*)&A[k][ty * 8];
            float4 a1 = *(const float4*)&A[k][ty * 8 + 4];
            float4 b0 = *(const float4*)&Bs[k][tx * 4];
            float4 b1 = *(const float4*)&Bs[k][64 + tx * 4];
            float4 b2 = *(const float4*)&Bs[k][128 + tx * 4];
            float4 b3 = *(const float4*)&Bs[k][192 + tx * 4];
            const float ar[8] = {a0.x, a0.y, a0.z, a0.w, a1.x, a1.y, a1.z, a1.w};
            const float br[16] = {b0.x, b0.y, b0.z, b0.w, b1.x, b1.y, b1.z, b1.w,
                                  b2.x, b2.y, b2.z, b2.w, b3.x, b3.y, b3.z, b3.w};
#pragma unroll
            for (int i = 0; i < 8; ++i)
#pragma unroll
                for (int n = 0; n < 16; ++n) acc[i][n] += ar[i] * br[n];
        }
    }

    // Epilogue: + bias, store.
    float bfr[16];
#pragma unroll
    for (int g = 0; g < 4; ++g) {
        float4 bb = *(const float4*)(bias + d * NG4 + ct * 256 + g * 64 + tx * 4);
        bfr[g * 4 + 0] = bb.x; bfr[g * 4 + 1] = bb.y; bfr[g * 4 + 2] = bb.z; bfr[g * 4 + 3] = bb.w;
    }
#pragma unroll
    for (int i = 0; i < 8; ++i) {
        const int s = ty * 8 + i;
        float* zp = zin + (((size_t)(d * NB + b) * CHUNK + s)) * NG4 + ct * 256;
#pragma unroll
        for (int g = 0; g < 4; ++g) {
            float4 o;
            o.x = acc[i][g * 4 + 0] + bfr[g * 4 + 0];
            o.y = acc[i][g * 4 + 1] + bfr[g * 4 + 1];
            o.z = acc[i][g * 4 + 2] + bfr[g * 4 + 2];
            o.w = acc[i][g * 4 + 3] + bfr[g * 4 + 3];
            *(float4*)(zp + g * 64 + tx * 4) = o;
        }
    }
}

// ---------------------------------------------------------------------------
// Recurrent kernel: one block per (d,b). Whh rows in VGPRs, h broadcast via LDS.
// ---------------------------------------------------------------------------
__global__ __launch_bounds__(1024) void lstm_rec_kernel(
    const float* __restrict__ Whh,     // [2][512][128]
    const float* __restrict__ zin,     // [2][B][CHUNK][512]
    float*       __restrict__ hout,    // [B][T][256]; slice [d*128, d*128+128)
    float*       __restrict__ state_h, // [2][B][128]
    float*       __restrict__ state_c, // [2][B][128]
    int c)
{
    __shared__ __align__(16) float h_lds[128];
    __shared__ float p_lds[1024];

    const int bid = blockIdx.x;  // d*128 + b
    const int d = bid >> 7, b = bid & 127;
    const int tid = threadIdx.x;
    const int j = tid & 511, q = tid >> 9;

    float w[64];
    const float* wrow = Whh + ((size_t)(d * NG4 + j)) * NH + q * 64;
#pragma unroll
    for (int kk = 0; kk < 64; kk += 4) {
        float4 t4 = *(const float4*)(wrow + kk);
        w[kk] = t4.x; w[kk + 1] = t4.y; w[kk + 2] = t4.z; w[kk + 3] = t4.w;
    }

    float c_reg = 0.0f;
    if (tid < 128) {
        float h0 = 0.0f;
        if (c != 0) {
            h0    = state_h[(d * NB + b) * NH + tid];
            c_reg = state_c[(d * NB + b) * NH + tid];
        }
        h_lds[tid] = h0;
    }
    __syncthreads();

    const float* zb = zin + ((size_t)(d * NB + b)) * CHUNK * NG4;

    for (int s = 0; s < CHUNK; ++s) {
        float z0 = 0.f, z1 = 0.f, z2 = 0.f, z3 = 0.f;
        if (tid < 128) {
            const float* zr = zb + (size_t)s * NG4;
            z0 = zr[tid]; z1 = zr[128 + tid]; z2 = zr[256 + tid]; z3 = zr[384 + tid];
        }
        float acc = 0.0f;
        const float* hp = h_lds + q * 64;
#pragma unroll
        for (int kk = 0; kk < 64; kk += 4) {
            float4 hv = *(const float4*)(hp + kk);
            acc += w[kk] * hv.x + w[kk + 1] * hv.y + w[kk + 2] * hv.z + w[kk + 3] * hv.w;
        }
        p_lds[tid] = acc;
        __syncthreads();

        if (tid < 128) {
            const float zi = z0 + p_lds[tid]       + p_lds[512 + tid];
            const float zf = z1 + p_lds[128 + tid] + p_lds[640 + tid];
            const float zg = z2 + p_lds[256 + tid] + p_lds[768 + tid];
            const float zo = z3 + p_lds[384 + tid] + p_lds[896 + tid];
            const float ig = sigf(zi), fg = sigf(zf), og = sigf(zo);
            c_reg = fg * c_reg + ig * tanhf(zg);
            const float hn = og * tanhf(c_reg);
            const int ttl = c * CHUNK + s;
            const int t   = d ? (NT - 1 - ttl) : ttl;
            h_lds[tid] = hn;
            hout[((size_t)(b * NT + t)) * 256 + d * NH + tid] = hn;
        }
        __syncthreads();
    }

    if (tid < 128) {
        state_h[(d * NB + b) * NH + tid] = h_lds[tid];
        state_c[(d * NB + b) * NH + tid] = c_reg;
    }
}

// ---------------------------------------------------------------------------
// Fused emissions + Viterbi. One block (256 thr) per batch row.
// Phase 1 (4 waves): em[b] = h2[b] @ Wout^T + bout  -> LDS (same fp expression
//   order as the R2 emis kernel -> bit-identical em values).
// Phase 2 (wave 0 only): register-resident scan. Lane j (both halves) holds
//   score[j]; half h reduces i in [h*16,h*16+16) via in-lane argmax tree
//   (left-preferred >= == first-index-wins), cross-half combine via shfl.
//   No barriers / no LDS on the critical path. hist bytes -> LDS.
// Phase 3 (lane 0): LDS backtrack.
// ---------------------------------------------------------------------------
__global__ __launch_bounds__(256) void viterbi_fused(
    const float* __restrict__ h2,      // [B][T][256]
    const float* __restrict__ Wout,    // [32][256]
    const float* __restrict__ bout,    // [32]
    const float* __restrict__ start_t, // [32]
    const float* __restrict__ end_t,   // [32]
    const float* __restrict__ trans,   // [32][32]
    int*         __restrict__ out)     // [B][T]
{
    __shared__ float wt[256 * 32];                // Wout transposed [c][k]
    __shared__ __align__(16) float hrow[8][256];
    __shared__ float em_s[NT * NKT];              // 64 KiB
    __shared__ unsigned char hist[(NT - 1) * 32];

    const int b = blockIdx.x;
    const int tid = threadIdx.x;
    const int k = tid & 31;
    const int rl = tid >> 5;  // 0..7

    // ---- Phase 1: emissions into LDS ----
    for (int e = tid; e < 8192; e += 256) {
        const int kk = e >> 8, cc = e & 255;
        wt[cc * 32 + kk] = Wout[e];
    }
    const float bk = bout[k];
    __syncthreads();

    const float* h2b = h2 + (size_t)b * NT * 256;
    for (int rr = 0; rr < 64; ++rr) {
        const int r0 = rr * 8;
        for (int e = tid; e < 512; e += 256) {
            ((float4*)&hrow[0][0])[e] = ((const float4*)(h2b + (size_t)r0 * 256))[e];
        }
        __syncthreads();
        float acc = bk;
#pragma unroll 8
        for (int cc = 0; cc < 256; cc += 4) {
            float4 hv = *(const float4*)&hrow[rl][cc];
            acc += hv.x * wt[cc * 32 + k] + hv.y * wt[(cc + 1) * 32 + k] +
                   hv.z * wt[(cc + 2) * 32 + k] + hv.w * wt[(cc + 3) * 32 + k];
        }
        em_s[(r0 + rl) * NKT + k] = acc;
        __syncthreads();
    }

    // ---- Phase 2: scan (wave 0 only; no further barriers) ----
    if (tid >= 64) return;
    const int lane = tid;
    const int j = lane & 31;
    const int h = lane >> 5;

    float tr_reg[16];
#pragma unroll
    for (int ii = 0; ii < 16; ++ii) tr_reg[ii] = trans[(h * 16 + ii) * 32 + j];
    const float et = end_t[j];

    float score = start_t[j] + em_s[j];
    float em_cur = em_s[NKT + j];  // t = 1

    for (int t = 1; t < NT; ++t) {
        const float em_nxt = (t + 1 < NT) ? em_s[(t + 1) * NKT + j] : 0.0f;

        // candidates for i = h*16 + ii; score[i] lives in lane h*48 + ii
        float v[16];
#pragma unroll
        for (int ii = 0; ii < 16; ++ii) {
            const float si = __shfl(score, h * 48 + ii);
            v[ii] = (si + tr_reg[ii]) + em_cur;  // np add order
        }
        // in-lane argmax tree, left (lower index) preferred on ties
        float l1v[8]; int l1i[8];
#pragma unroll
        for (int p = 0; p < 8; ++p) {
            const bool L = v[2 * p] >= v[2 * p + 1];
            l1v[p] = L ? v[2 * p] : v[2 * p + 1];
            l1i[p] = L ? 2 * p : 2 * p + 1;
        }
        float l2v[4]; int l2i[4];
#pragma unroll
        for (int p = 0; p < 4; ++p) {
            const bool L = l1v[2 * p] >= l1v[2 * p + 1];
            l2v[p] = L ? l1v[2 * p] : l1v[2 * p + 1];
            l2i[p] = L ? l1i[2 * p] : l1i[2 * p + 1];
        }
        float l3v[2]; int l3i[2];
#pragma unroll
        for (int p = 0; p < 2; ++p) {
            const bool L = l2v[2 * p] >= l2v[2 * p + 1];
            l3v[p] = L ? l2v[2 * p] : l2v[2 * p + 1];
            l3i[p] = L ? l2i[2 * p] : l2i[2 * p + 1];
        }
        const bool L4 = l3v[0] >= l3v[1];
        const float best = L4 ? l3v[0] : l3v[1];
        const int   bi   = h * 16 + (L4 ? l3i[0] : l3i[1]);

        // cross-half combine (low half wins ties -> smaller i)
        const float ob  = __shfl(best, lane ^ 32);
        const int   obi = __shfl(bi,   lane ^ 32);
        const bool take_other = h ? (ob >= best) : (ob > best);
        const float ns = take_other ? ob : best;
        const int  arg = take_other ? obi : bi;

        if (h == 0) hist[(t - 1) * 32 + j] = (unsigned char)arg;
        score = ns;
        em_cur = em_nxt;
    }

    // final argmax over j (first-index-wins butterfly)
    float fv = score + et;
    int fi = j;
#pragma unroll
    for (int dlt = 1; dlt <= 16; dlt <<= 1) {
        const float vo = __shfl_xor(fv, dlt);
        const int   io = __shfl_xor(fi, dlt);
        if (vo > fv || (vo == fv && io < fi)) { fv = vo; fi = io; }
    }

    // ---- Phase 3: backtrack ----
    if (lane == 0) {
        int tag = fi;
        out[b * NT + (NT - 1)] = tag;
        for (int t = NT - 2; t >= 0; --t) {
            tag = hist[t * 32 + tag];
            out[b * NT + t] = tag;
        }
    }
}

// ---------------------------------------------------------------------------
extern "C" void kernel_launch(void* const* d_in, const int* in_sizes, int n_in,
                              void* d_out, int out_size, void* d_ws, size_t ws_size,
                              hipStream_t stream) {
    const int*   inputs  = (const int*)d_in[0];
    // d_in[1] = tags (unused by forward/decode)
    const float* emb     = (const float*)d_in[2];
    const float* w_ih_l0 = (const float*)d_in[3];
    const float* w_hh_l0 = (const float*)d_in[4];
    const float* b_l0    = (const float*)d_in[5];
    const float* w_ih_l1 = (const float*)d_in[6];
    const float* w_hh_l1 = (const float*)d_in[7];
    const float* b_l1    = (const float*)d_in[8];
    const float* W_out   = (const float*)d_in[9];
    const float* b_out   = (const float*)d_in[10];
    const float* start_t = (const float*)d_in[11];
    const float* end_t   = (const float*)d_in[12];
    const float* trans   = (const float*)d_in[13];
    int* out = (int*)d_out;

    float* ws  = (float*)d_ws;
    float* zin = ws;                                        // 2*B*CHUNK*512
    float* h1  = zin + (size_t)2 * NB * CHUNK * NG4;        // B*T*256
    float* h2  = h1 + (size_t)NB * NT * 256;                // B*T*256
    float* sth = h2 + (size_t)NB * NT * 256;                // 2*B*128
    float* stc = sth + (size_t)2 * NB * NH;                 // 2*B*128

    // Layer 0: chunked input-projection GEMM + recurrence
    for (int c = 0; c < NCH; ++c) {
        proj_gemm<128><<<512, 256, 0, stream>>>(w_ih_l0, b_l0, emb, inputs, zin, c);
        lstm_rec_kernel<<<256, 1024, 0, stream>>>(w_hh_l0, zin, h1, sth, stc, c);
    }
    // Layer 1
    for (int c = 0; c < NCH; ++c) {
        proj_gemm<256><<<512, 256, 0, stream>>>(w_ih_l1, b_l1, h1, nullptr, zin, c);
        lstm_rec_kernel<<<256, 1024, 0, stream>>>(w_hh_l1, zin, h2, sth, stc, c);
    }
    // Fused emissions + Viterbi decode
    viterbi_fused<<<NB, 256, 0, stream>>>(h2, W_out, b_out, start_t, end_t, trans, out);
}

// Round 4
// 2228.021 us; speedup vs baseline: 1.1617x; 1.1617x over previous
//
#include <hip/hip_runtime.h>
#include <cmath>

// Problem constants
static constexpr int NB   = 128;   // batch
static constexpr int NT   = 512;   // time
static constexpr int ND   = 128;   // embed dim
static constexpr int NH   = 128;   // hidden per direction
static constexpr int NG4  = 512;   // 4*H
static constexpr int NKT  = 32;    // num tags
static constexpr int CHUNK = 128;  // timesteps per chunk
static constexpr int NCH  = NT / CHUNK;

__device__ __forceinline__ float sigf(float x) { return 1.0f / (1.0f + expf(-x)); }

// ---------------------------------------------------------------------------
// Projection GEMM: zin[d][b][s][j] = bias[d][j] + sum_k Wih[d][j][k] * X(b,t(d,c,s),k)
// 512 threads, tile 128(s) x 256(j), thread tile 8x8 (~120 VGPR, no spill),
// double-buffered LDS, ONE barrier per K-step. Same k-ascending accumulation
// order as before -> bit-identical zin.
// grid = 512: bid = d*256 + b*2 + ct
// ---------------------------------------------------------------------------
template <int DIN>
__global__ __launch_bounds__(512) void proj_gemm8(
    const float* __restrict__ Wih,    // [2][512][DIN]
    const float* __restrict__ bias,   // [2][512]
    const float* __restrict__ xsrc,   // emb [V][128] (l0) or h1 [B][T][256] (l1)
    const int*   __restrict__ inputs, // [B][T] (l0 only)
    float*       __restrict__ zin,    // [2][B][CHUNK][512]
    int c)
{
    constexpr int KT = DIN / 16;
    __shared__ __align__(16) float A[2][16][128];
    __shared__ __align__(16) float Bs[2][16][256];
    __shared__ const float* rowp[128];

    const int bid = blockIdx.x;
    const int d  = bid >> 8;
    const int b  = (bid >> 1) & 127;
    const int ct = bid & 1;
    const int tid = threadIdx.x;
    const int tx = tid & 31;    // cols: ct*256 + {tx*4..+3, 128+tx*4..+3}
    const int ty = tid >> 5;    // rows: ty*8 .. ty*8+7
    const int a_r = tid & 127;  // A staging row
    const int a_k = tid >> 7;   // A staging k-quarter (0..3)
    const int b_j = tid & 255;  // B staging row (col j)
    const int b_h = tid >> 8;   // B staging k-half (0..1)

    if (tid < 128) {
        const int s = tid;
        const int ttl = c * CHUNK + s;
        const int t = d ? (NT - 1 - ttl) : ttl;
        if constexpr (DIN == 128) {
            rowp[tid] = xsrc + (size_t)inputs[b * NT + t] * ND;
        } else {
            rowp[tid] = xsrc + ((size_t)(b * NT + t)) * 256;
        }
    }
    __syncthreads();

    const float* arow = rowp[a_r];
    const float* wrow = Wih + ((size_t)(d * NG4 + ct * 256 + b_j)) * DIN;

    float acc[8][8];
#pragma unroll
    for (int i = 0; i < 8; ++i)
#pragma unroll
        for (int n = 0; n < 8; ++n) acc[i][n] = 0.0f;

    // Prefetch kt=0.
    float4 pa  = *(const float4*)(arow + a_k * 4);
    float4 pb0 = *(const float4*)(wrow + b_h * 8);
    float4 pb1 = *(const float4*)(wrow + b_h * 8 + 4);

    for (int kt = 0; kt < KT; ++kt) {
        const int buf = kt & 1;
        // Write staged regs -> LDS (other buffer than the one still being read
        // by any lagging wave — single barrier is sufficient, see analysis).
        A[buf][a_k * 4 + 0][a_r] = pa.x;
        A[buf][a_k * 4 + 1][a_r] = pa.y;
        A[buf][a_k * 4 + 2][a_r] = pa.z;
        A[buf][a_k * 4 + 3][a_r] = pa.w;
        Bs[buf][b_h * 8 + 0][b_j] = pb0.x;
        Bs[buf][b_h * 8 + 1][b_j] = pb0.y;
        Bs[buf][b_h * 8 + 2][b_j] = pb0.z;
        Bs[buf][b_h * 8 + 3][b_j] = pb0.w;
        Bs[buf][b_h * 8 + 4][b_j] = pb1.x;
        Bs[buf][b_h * 8 + 5][b_j] = pb1.y;
        Bs[buf][b_h * 8 + 6][b_j] = pb1.z;
        Bs[buf][b_h * 8 + 7][b_j] = pb1.w;
        __syncthreads();

        if (kt + 1 < KT) {
            const int k0 = (kt + 1) * 16;
            pa  = *(const float4*)(arow + k0 + a_k * 4);
            pb0 = *(const float4*)(wrow + k0 + b_h * 8);
            pb1 = *(const float4*)(wrow + k0 + b_h * 8 + 4);
        }

#pragma unroll 2
        for (int k = 0; k < 16; ++k) {
            float4 a0 = *(const float4*)&A[buf][k][ty * 8];
            float4 a1 = *(const float4*)&A[buf][k][ty * 8 + 4];
            float4 b0 = *(const float4*)&Bs[buf][k][tx * 4];
            float4 b1 = *(const float4*)&Bs[buf][k][128 + tx * 4];
            const float ar[8] = {a0.x, a0.y, a0.z, a0.w, a1.x, a1.y, a1.z, a1.w};
            const float br[8] = {b0.x, b0.y, b0.z, b0.w, b1.x, b1.y, b1.z, b1.w};
#pragma unroll
            for (int i = 0; i < 8; ++i)
#pragma unroll
                for (int n = 0; n < 8; ++n) acc[i][n] += ar[i] * br[n];
        }
    }

    // Epilogue: + bias, store.
    float4 bb0 = *(const float4*)(bias + d * NG4 + ct * 256 + tx * 4);
    float4 bb1 = *(const float4*)(bias + d * NG4 + ct * 256 + 128 + tx * 4);
#pragma unroll
    for (int i = 0; i < 8; ++i) {
        const int s = ty * 8 + i;
        float* zp = zin + (((size_t)(d * NB + b) * CHUNK + s)) * NG4 + ct * 256;
        float4 o0, o1;
        o0.x = acc[i][0] + bb0.x; o0.y = acc[i][1] + bb0.y;
        o0.z = acc[i][2] + bb0.z; o0.w = acc[i][3] + bb0.w;
        o1.x = acc[i][4] + bb1.x; o1.y = acc[i][5] + bb1.y;
        o1.z = acc[i][6] + bb1.z; o1.w = acc[i][7] + bb1.w;
        *(float4*)(zp + tx * 4) = o0;
        *(float4*)(zp + 128 + tx * 4) = o1;
    }
}

// ---------------------------------------------------------------------------
// Recurrent kernel: one block (512 thr) per (d,b). Thread j owns the FULL
// 128-k dot of Whh row j (no partial-sum round trip). h broadcast via LDS.
// ---------------------------------------------------------------------------
__global__ __launch_bounds__(512) void lstm_rec512(
    const float* __restrict__ Whh,     // [2][512][128]
    const float* __restrict__ zin,     // [2][B][CHUNK][512]
    float*       __restrict__ hout,    // [B][T][256]; slice [d*128, d*128+128)
    float*       __restrict__ state_h, // [2][B][128]
    float*       __restrict__ state_c, // [2][B][128]
    int c)
{
    __shared__ __align__(16) float h_lds[128];
    __shared__ float p_lds[512];

    const int bid = blockIdx.x;  // d*128 + b
    const int d = bid >> 7, b = bid & 127;
    const int j = threadIdx.x;   // 0..511

    float w[128];
    const float* wrow = Whh + ((size_t)(d * NG4 + j)) * NH;
#pragma unroll
    for (int kk = 0; kk < 128; kk += 4) {
        float4 t4 = *(const float4*)(wrow + kk);
        w[kk] = t4.x; w[kk + 1] = t4.y; w[kk + 2] = t4.z; w[kk + 3] = t4.w;
    }

    float c_reg = 0.0f;
    if (j < 128) {
        float h0 = 0.0f;
        if (c != 0) {
            h0    = state_h[(d * NB + b) * NH + j];
            c_reg = state_c[(d * NB + b) * NH + j];
        }
        h_lds[j] = h0;
    }
    __syncthreads();

    const float* zb = zin + ((size_t)(d * NB + b)) * CHUNK * NG4;

    for (int s = 0; s < CHUNK; ++s) {
        float z0 = 0.f, z1 = 0.f, z2 = 0.f, z3 = 0.f;
        if (j < 128) {
            const float* zr = zb + (size_t)s * NG4;
            z0 = zr[j]; z1 = zr[128 + j]; z2 = zr[256 + j]; z3 = zr[384 + j];
        }
        float acc = 0.0f;
#pragma unroll
        for (int kk = 0; kk < 128; kk += 4) {
            float4 hv = *(const float4*)&h_lds[kk];
            acc += w[kk] * hv.x + w[kk + 1] * hv.y + w[kk + 2] * hv.z + w[kk + 3] * hv.w;
        }
        p_lds[j] = acc;
        __syncthreads();

        if (j < 128) {
            const float zi = z0 + p_lds[j];
            const float zf = z1 + p_lds[128 + j];
            const float zg = z2 + p_lds[256 + j];
            const float zo = z3 + p_lds[384 + j];
            const float ig = sigf(zi), fg = sigf(zf), og = sigf(zo);
            c_reg = fg * c_reg + ig * tanhf(zg);
            const float hn = og * tanhf(c_reg);
            const int ttl = c * CHUNK + s;
            const int t   = d ? (NT - 1 - ttl) : ttl;
            h_lds[j] = hn;
            hout[((size_t)(b * NT + t)) * 256 + d * NH + j] = hn;
        }
        __syncthreads();
    }

    if (j < 128) {
        state_h[(d * NB + b) * NH + j] = h_lds[j];
        state_c[(d * NB + b) * NH + j] = c_reg;
    }
}

// ---------------------------------------------------------------------------
// Emissions: em[b][t][k] = b_out[k] + sum_c h2[b][t][c] * W_out[k][c]
// 1024 blocks x 256 threads (throughput-shaped; proven ~50us).
// ---------------------------------------------------------------------------
__global__ __launch_bounds__(256) void emis_kernel(
    const float* __restrict__ h2,    // [B][T][256]
    const float* __restrict__ Wout,  // [32][256]
    const float* __restrict__ bout,  // [32]
    float*       __restrict__ em)    // [B][T][32]
{
    __shared__ float wt[256 * 32];               // transposed [c][k]
    __shared__ __align__(16) float hrow[8][256];

    const int tid = threadIdx.x;
    const int k = tid & 31;
    const int rl = tid >> 5;  // 0..7

    for (int e = tid; e < 8192; e += 256) {
        const int kk = e >> 8, cc = e & 255;
        wt[cc * 32 + kk] = Wout[e];
    }
    const float bk = bout[k];
    __syncthreads();

    const size_t base = (size_t)blockIdx.x * 64;
    for (int rr = 0; rr < 8; ++rr) {
        const size_t r0 = base + rr * 8;
        for (int e = tid; e < 512; e += 256) {
            ((float4*)&hrow[0][0])[e] = ((const float4*)(h2 + r0 * 256))[e];
        }
        __syncthreads();
        float acc = bk;
#pragma unroll 8
        for (int cc = 0; cc < 256; cc += 4) {
            float4 hv = *(const float4*)&hrow[rl][cc];
            acc += hv.x * wt[cc * 32 + k] + hv.y * wt[(cc + 1) * 32 + k] +
                   hv.z * wt[(cc + 2) * 32 + k] + hv.w * wt[(cc + 3) * 32 + k];
        }
        em[(r0 + rl) * NKT + k] = acc;
        __syncthreads();
    }
}

// ---------------------------------------------------------------------------
// Viterbi: one block (1 wave) per batch row. em staged to LDS once, then
// register-resident scan (proven in R3): lane j holds score[j] in both halves;
// half h reduces i in [h*16,h*16+16) via in-lane argmax tree (left-preferred
// >= == first-index-wins), cross-half combine via shfl. Zero barriers in loop.
// ---------------------------------------------------------------------------
__global__ __launch_bounds__(64) void viterbi_reg(
    const float* __restrict__ em,      // [B][T][32]
    const float* __restrict__ start_t, // [32]
    const float* __restrict__ end_t,   // [32]
    const float* __restrict__ trans,   // [32][32]
    int*         __restrict__ out)     // [B][T]
{
    __shared__ __align__(16) float em_s[NT * NKT];   // 64 KiB
    __shared__ unsigned char hist[(NT - 1) * 32];

    const int b = blockIdx.x;
    const int lane = threadIdx.x;
    const int j = lane & 31;
    const int h = lane >> 5;

    const float* embase = em + (size_t)b * NT * NKT;
    for (int e = lane; e < NT * NKT / 4; e += 64) {
        ((float4*)em_s)[e] = ((const float4*)embase)[e];
    }

    float tr_reg[16];
#pragma unroll
    for (int ii = 0; ii < 16; ++ii) tr_reg[ii] = trans[(h * 16 + ii) * 32 + j];
    const float et = end_t[j];
    const float st = start_t[j];
    __syncthreads();

    float score = st + em_s[j];
    float em_cur = em_s[NKT + j];  // t = 1

    for (int t = 1; t < NT; ++t) {
        const float em_nxt = (t + 1 < NT) ? em_s[(t + 1) * NKT + j] : 0.0f;

        float v[16];
#pragma unroll
        for (int ii = 0; ii < 16; ++ii) {
            const float si = __shfl(score, h * 48 + ii);  // score[h*16+ii]
            v[ii] = (si + tr_reg[ii]) + em_cur;           // np add order
        }
        float l1v[8]; int l1i[8];
#pragma unroll
        for (int p = 0; p < 8; ++p) {
            const bool L = v[2 * p] >= v[2 * p + 1];
            l1v[p] = L ? v[2 * p] : v[2 * p + 1];
            l1i[p] = L ? 2 * p : 2 * p + 1;
        }
        float l2v[4]; int l2i[4];
#pragma unroll
        for (int p = 0; p < 4; ++p) {
            const bool L = l1v[2 * p] >= l1v[2 * p + 1];
            l2v[p] = L ? l1v[2 * p] : l1v[2 * p + 1];
            l2i[p] = L ? l1i[2 * p] : l1i[2 * p + 1];
        }
        float l3v[2]; int l3i[2];
#pragma unroll
        for (int p = 0; p < 2; ++p) {
            const bool L = l2v[2 * p] >= l2v[2 * p + 1];
            l3v[p] = L ? l2v[2 * p] : l2v[2 * p + 1];
            l3i[p] = L ? l2i[2 * p] : l2i[2 * p + 1];
        }
        const bool L4 = l3v[0] >= l3v[1];
        const float best = L4 ? l3v[0] : l3v[1];
        const int   bi   = h * 16 + (L4 ? l3i[0] : l3i[1]);

        const float ob  = __shfl(best, lane ^ 32);
        const int   obi = __shfl(bi,   lane ^ 32);
        const bool take_other = h ? (ob >= best) : (ob > best);  // ties -> low half
        const float ns = take_other ? ob : best;
        const int  arg = take_other ? obi : bi;

        if (h == 0) hist[(t - 1) * 32 + j] = (unsigned char)arg;
        score = ns;
        em_cur = em_nxt;
    }

    // final argmax over j (first-index-wins butterfly)
    float fv = score + et;
    int fi = j;
#pragma unroll
    for (int dlt = 1; dlt <= 16; dlt <<= 1) {
        const float vo = __shfl_xor(fv, dlt);
        const int   io = __shfl_xor(fi, dlt);
        if (vo > fv || (vo == fv && io < fi)) { fv = vo; fi = io; }
    }

    if (lane == 0) {
        int tag = fi;
        out[b * NT + (NT - 1)] = tag;
        for (int t = NT - 2; t >= 0; --t) {
            tag = hist[t * 32 + tag];
            out[b * NT + t] = tag;
        }
    }
}

// ---------------------------------------------------------------------------
extern "C" void kernel_launch(void* const* d_in, const int* in_sizes, int n_in,
                              void* d_out, int out_size, void* d_ws, size_t ws_size,
                              hipStream_t stream) {
    const int*   inputs  = (const int*)d_in[0];
    // d_in[1] = tags (unused by forward/decode)
    const float* emb     = (const float*)d_in[2];
    const float* w_ih_l0 = (const float*)d_in[3];
    const float* w_hh_l0 = (const float*)d_in[4];
    const float* b_l0    = (const float*)d_in[5];
    const float* w_ih_l1 = (const float*)d_in[6];
    const float* w_hh_l1 = (const float*)d_in[7];
    const float* b_l1    = (const float*)d_in[8];
    const float* W_out   = (const float*)d_in[9];
    const float* b_out   = (const float*)d_in[10];
    const float* start_t = (const float*)d_in[11];
    const float* end_t   = (const float*)d_in[12];
    const float* trans   = (const float*)d_in[13];
    int* out = (int*)d_out;

    float* ws  = (float*)d_ws;
    float* zin = ws;                                        // 2*B*CHUNK*512
    float* h1  = zin + (size_t)2 * NB * CHUNK * NG4;        // B*T*256
    float* h2  = h1 + (size_t)NB * NT * 256;                // B*T*256
    float* sth = h2 + (size_t)NB * NT * 256;                // 2*B*128
    float* stc = sth + (size_t)2 * NB * NH;                 // 2*B*128
    float* em  = stc + (size_t)2 * NB * NH;                 // B*T*32

    // Layer 0: chunked input-projection GEMM + recurrence
    for (int c = 0; c < NCH; ++c) {
        proj_gemm8<128><<<512, 512, 0, stream>>>(w_ih_l0, b_l0, emb, inputs, zin, c);
        lstm_rec512<<<256, 512, 0, stream>>>(w_hh_l0, zin, h1, sth, stc, c);
    }
    // Layer 1
    for (int c = 0; c < NCH; ++c) {
        proj_gemm8<256><<<512, 512, 0, stream>>>(w_ih_l1, b_l1, h1, nullptr, zin, c);
        lstm_rec512<<<256, 512, 0, stream>>>(w_hh_l1, zin, h2, sth, stc, c);
    }
    // Emissions + Viterbi decode
    emis_kernel<<<(NB * NT) / 64, 256, 0, stream>>>(h2, W_out, b_out, em);
    viterbi_reg<<<NB, 64, 0, stream>>>(em, start_t, end_t, trans, out);
}

// Round 5
// 2194.558 us; speedup vs baseline: 1.1794x; 1.0152x over previous
//
#include <hip/hip_runtime.h>
#include <cmath>

// Problem constants
static constexpr int NB   = 128;   // batch
static constexpr int NT   = 512;   // time
static constexpr int ND   = 128;   // embed dim
static constexpr int NH   = 128;   // hidden per direction
static constexpr int NG4  = 512;   // 4*H
static constexpr int NKT  = 32;    // num tags
static constexpr int CHUNK = 128;  // timesteps per chunk
static constexpr int NCH  = NT / CHUNK;

__device__ __forceinline__ float sigf(float x) { return 1.0f / (1.0f + expf(-x)); }

// ---------------------------------------------------------------------------
// Projection GEMM: zin[d][b][s][j] = bias[d][j] + sum_k Wih[d][j][k] * X(b,t(d,c,s),k)
// 256 threads, tile 128(s) x 256(j), thread tile 16 rows x 8 cols.
// A-fragment reads are LDS *broadcast* (lanes in a ty-group share addresses)
// => LDS bank traffic ~30% of VALU => VALU-bound (R4's 8x8 was LDS-co-limited).
// Same k-ascending per-element FMA chain + bias at end -> zin bitwise == R4.
// grid = 512: bid = d*256 + b*2 + ct
// ---------------------------------------------------------------------------
template <int DIN>
__global__ __launch_bounds__(256) void proj_gemm16x8(
    const float* __restrict__ Wih,    // [2][512][DIN]
    const float* __restrict__ bias,   // [2][512]
    const float* __restrict__ xsrc,   // emb [V][128] (l0) or h1 [B][T][256] (l1)
    const int*   __restrict__ inputs, // [B][T] (l0 only)
    float*       __restrict__ zin,    // [2][B][CHUNK][512]
    int c)
{
    constexpr int KT = DIN / 16;
    __shared__ __align__(16) float A[2][16][128];
    __shared__ __align__(16) float Bs[2][16][256];
    __shared__ const float* rowp[128];

    const int bid = blockIdx.x;
    const int d  = bid >> 8;
    const int b  = (bid >> 1) & 127;
    const int ct = bid & 1;
    const int tid = threadIdx.x;
    const int tx = tid & 31;    // cols: ct*256 + {tx*4..+3, 128+tx*4..+3}
    const int ty = tid >> 5;    // rows: ty*16 .. ty*16+15
    const int a_r = tid & 127;  // A staging row
    const int a_k = tid >> 7;   // A staging k-half (0/1): k = a_k*8..+7

    if (tid < 128) {
        const int s = tid;
        const int ttl = c * CHUNK + s;
        const int t = d ? (NT - 1 - ttl) : ttl;
        if constexpr (DIN == 128) {
            rowp[tid] = xsrc + (size_t)inputs[b * NT + t] * ND;
        } else {
            rowp[tid] = xsrc + ((size_t)(b * NT + t)) * 256;
        }
    }
    __syncthreads();

    const float* arow = rowp[a_r];
    const float* wrow = Wih + ((size_t)(d * NG4 + ct * 256 + tid)) * DIN;

    float acc[16][8];
#pragma unroll
    for (int i = 0; i < 16; ++i)
#pragma unroll
        for (int n = 0; n < 8; ++n) acc[i][n] = 0.0f;

    // Prefetch kt=0 into registers.
    float4 pa0 = *(const float4*)(arow + a_k * 8);
    float4 pa1 = *(const float4*)(arow + a_k * 8 + 4);
    float4 pb0 = *(const float4*)(wrow + 0);
    float4 pb1 = *(const float4*)(wrow + 4);
    float4 pb2 = *(const float4*)(wrow + 8);
    float4 pb3 = *(const float4*)(wrow + 12);

    for (int kt = 0; kt < KT; ++kt) {
        const int buf = kt & 1;
        // Stage A: A[a_k*8 + r][a_r]
        A[buf][a_k * 8 + 0][a_r] = pa0.x; A[buf][a_k * 8 + 1][a_r] = pa0.y;
        A[buf][a_k * 8 + 2][a_r] = pa0.z; A[buf][a_k * 8 + 3][a_r] = pa0.w;
        A[buf][a_k * 8 + 4][a_r] = pa1.x; A[buf][a_k * 8 + 5][a_r] = pa1.y;
        A[buf][a_k * 8 + 6][a_r] = pa1.z; A[buf][a_k * 8 + 7][a_r] = pa1.w;
        // Stage B transposed: Bs[k][tid], k = 0..15 (col j = ct*256+tid)
        Bs[buf][ 0][tid] = pb0.x; Bs[buf][ 1][tid] = pb0.y;
        Bs[buf][ 2][tid] = pb0.z; Bs[buf][ 3][tid] = pb0.w;
        Bs[buf][ 4][tid] = pb1.x; Bs[buf][ 5][tid] = pb1.y;
        Bs[buf][ 6][tid] = pb1.z; Bs[buf][ 7][tid] = pb1.w;
        Bs[buf][ 8][tid] = pb2.x; Bs[buf][ 9][tid] = pb2.y;
        Bs[buf][10][tid] = pb2.z; Bs[buf][11][tid] = pb2.w;
        Bs[buf][12][tid] = pb3.x; Bs[buf][13][tid] = pb3.y;
        Bs[buf][14][tid] = pb3.z; Bs[buf][15][tid] = pb3.w;
        __syncthreads();

        if (kt + 1 < KT) {
            const int k0 = (kt + 1) * 16;
            pa0 = *(const float4*)(arow + k0 + a_k * 8);
            pa1 = *(const float4*)(arow + k0 + a_k * 8 + 4);
            pb0 = *(const float4*)(wrow + k0 + 0);
            pb1 = *(const float4*)(wrow + k0 + 4);
            pb2 = *(const float4*)(wrow + k0 + 8);
            pb3 = *(const float4*)(wrow + k0 + 12);
        }

#pragma unroll 2
        for (int k = 0; k < 16; ++k) {
            float4 a0 = *(const float4*)&A[buf][k][ty * 16];
            float4 a1 = *(const float4*)&A[buf][k][ty * 16 + 4];
            float4 a2 = *(const float4*)&A[buf][k][ty * 16 + 8];
            float4 a3 = *(const float4*)&A[buf][k][ty * 16 + 12];
            float4 b0 = *(const float4*)&Bs[buf][k][tx * 4];
            float4 b1 = *(const float4*)&Bs[buf][k][128 + tx * 4];
            const float ar[16] = {a0.x, a0.y, a0.z, a0.w, a1.x, a1.y, a1.z, a1.w,
                                  a2.x, a2.y, a2.z, a2.w, a3.x, a3.y, a3.z, a3.w};
            const float br[8]  = {b0.x, b0.y, b0.z, b0.w, b1.x, b1.y, b1.z, b1.w};
#pragma unroll
            for (int i = 0; i < 16; ++i)
#pragma unroll
                for (int n = 0; n < 8; ++n) acc[i][n] += ar[i] * br[n];
        }
    }

    // Epilogue: + bias, store.
    float4 bb0 = *(const float4*)(bias + d * NG4 + ct * 256 + tx * 4);
    float4 bb1 = *(const float4*)(bias + d * NG4 + ct * 256 + 128 + tx * 4);
#pragma unroll
    for (int i = 0; i < 16; ++i) {
        const int s = ty * 16 + i;
        float* zp = zin + (((size_t)(d * NB + b) * CHUNK + s)) * NG4 + ct * 256;
        float4 o0, o1;
        o0.x = acc[i][0] + bb0.x; o0.y = acc[i][1] + bb0.y;
        o0.z = acc[i][2] + bb0.z; o0.w = acc[i][3] + bb0.w;
        o1.x = acc[i][4] + bb1.x; o1.y = acc[i][5] + bb1.y;
        o1.z = acc[i][6] + bb1.z; o1.w = acc[i][7] + bb1.w;
        *(float4*)(zp + tx * 4) = o0;
        *(float4*)(zp + 128 + tx * 4) = o1;
    }
}

// ---------------------------------------------------------------------------
// Recurrent kernel: one block (512 thr) per (d,b). Thread j owns the FULL
// 128-k dot of Whh row j. h broadcast via LDS. (unchanged from R4)
// ---------------------------------------------------------------------------
__global__ __launch_bounds__(512) void lstm_rec512(
    const float* __restrict__ Whh,     // [2][512][128]
    const float* __restrict__ zin,     // [2][B][CHUNK][512]
    float*       __restrict__ hout,    // [B][T][256]; slice [d*128, d*128+128)
    float*       __restrict__ state_h, // [2][B][128]
    float*       __restrict__ state_c, // [2][B][128]
    int c)
{
    __shared__ __align__(16) float h_lds[128];
    __shared__ float p_lds[512];

    const int bid = blockIdx.x;  // d*128 + b
    const int d = bid >> 7, b = bid & 127;
    const int j = threadIdx.x;   // 0..511

    float w[128];
    const float* wrow = Whh + ((size_t)(d * NG4 + j)) * NH;
#pragma unroll
    for (int kk = 0; kk < 128; kk += 4) {
        float4 t4 = *(const float4*)(wrow + kk);
        w[kk] = t4.x; w[kk + 1] = t4.y; w[kk + 2] = t4.z; w[kk + 3] = t4.w;
    }

    float c_reg = 0.0f;
    if (j < 128) {
        float h0 = 0.0f;
        if (c != 0) {
            h0    = state_h[(d * NB + b) * NH + j];
            c_reg = state_c[(d * NB + b) * NH + j];
        }
        h_lds[j] = h0;
    }
    __syncthreads();

    const float* zb = zin + ((size_t)(d * NB + b)) * CHUNK * NG4;

    for (int s = 0; s < CHUNK; ++s) {
        float z0 = 0.f, z1 = 0.f, z2 = 0.f, z3 = 0.f;
        if (j < 128) {
            const float* zr = zb + (size_t)s * NG4;
            z0 = zr[j]; z1 = zr[128 + j]; z2 = zr[256 + j]; z3 = zr[384 + j];
        }
        float acc = 0.0f;
#pragma unroll
        for (int kk = 0; kk < 128; kk += 4) {
            float4 hv = *(const float4*)&h_lds[kk];
            acc += w[kk] * hv.x + w[kk + 1] * hv.y + w[kk + 2] * hv.z + w[kk + 3] * hv.w;
        }
        p_lds[j] = acc;
        __syncthreads();

        if (j < 128) {
            const float zi = z0 + p_lds[j];
            const float zf = z1 + p_lds[128 + j];
            const float zg = z2 + p_lds[256 + j];
            const float zo = z3 + p_lds[384 + j];
            const float ig = sigf(zi), fg = sigf(zf), og = sigf(zo);
            c_reg = fg * c_reg + ig * tanhf(zg);
            const float hn = og * tanhf(c_reg);
            const int ttl = c * CHUNK + s;
            const int t   = d ? (NT - 1 - ttl) : ttl;
            h_lds[j] = hn;
            hout[((size_t)(b * NT + t)) * 256 + d * NH + j] = hn;
        }
        __syncthreads();
    }

    if (j < 128) {
        state_h[(d * NB + b) * NH + j] = h_lds[j];
        state_c[(d * NB + b) * NH + j] = c_reg;
    }
}

// ---------------------------------------------------------------------------
// Emissions: em[b][t][k] = b_out[k] + sum_c h2[b][t][c] * W_out[k][c]
// (unchanged; ~50us)
// ---------------------------------------------------------------------------
__global__ __launch_bounds__(256) void emis_kernel(
    const float* __restrict__ h2,    // [B][T][256]
    const float* __restrict__ Wout,  // [32][256]
    const float* __restrict__ bout,  // [32]
    float*       __restrict__ em)    // [B][T][32]
{
    __shared__ float wt[256 * 32];               // transposed [c][k]
    __shared__ __align__(16) float hrow[8][256];

    const int tid = threadIdx.x;
    const int k = tid & 31;
    const int rl = tid >> 5;  // 0..7

    for (int e = tid; e < 8192; e += 256) {
        const int kk = e >> 8, cc = e & 255;
        wt[cc * 32 + kk] = Wout[e];
    }
    const float bk = bout[k];
    __syncthreads();

    const size_t base = (size_t)blockIdx.x * 64;
    for (int rr = 0; rr < 8; ++rr) {
        const size_t r0 = base + rr * 8;
        for (int e = tid; e < 512; e += 256) {
            ((float4*)&hrow[0][0])[e] = ((const float4*)(h2 + r0 * 256))[e];
        }
        __syncthreads();
        float acc = bk;
#pragma unroll 8
        for (int cc = 0; cc < 256; cc += 4) {
            float4 hv = *(const float4*)&hrow[rl][cc];
            acc += hv.x * wt[cc * 32 + k] + hv.y * wt[(cc + 1) * 32 + k] +
                   hv.z * wt[(cc + 2) * 32 + k] + hv.w * wt[(cc + 3) * 32 + k];
        }
        em[(r0 + rl) * NKT + k] = acc;
        __syncthreads();
    }
}

// ---------------------------------------------------------------------------
// Viterbi v3: one block (1 wave) per batch row.
// score in LDS (32 floats); per step the 16 scores a half needs are read as
// 4 broadcast float4 loads (one lgkm wait), candidates reduced by in-lane
// tree (left-preferred >= == first-index-wins), cross-half via 1 shfl.
// em read from GLOBAL with 2-deep register prefetch (no LDS staging).
// One __syncthreads per step (1-wave block: cheap). Decision semantics
// identical to R4 -> same tags.
// ---------------------------------------------------------------------------
__global__ __launch_bounds__(64) void viterbi_v3(
    const float* __restrict__ em,      // [B][T][32]
    const float* __restrict__ start_t, // [32]
    const float* __restrict__ end_t,   // [32]
    const float* __restrict__ trans,   // [32][32]
    int*         __restrict__ out)     // [B][T]
{
    __shared__ __align__(16) float score_s[32];
    __shared__ unsigned char hist[(NT - 1) * 32];

    const int b = blockIdx.x;
    const int lane = threadIdx.x;
    const int j = lane & 31;
    const int h = lane >> 5;

    float tr_reg[16];
#pragma unroll
    for (int ii = 0; ii < 16; ++ii) tr_reg[ii] = trans[(h * 16 + ii) * 32 + j];
    const float et = end_t[j];

    const float* embase = em + (size_t)b * NT * NKT;
    if (lane < 32) score_s[j] = start_t[j] + embase[j];
    __syncthreads();

    // 2-deep em prefetch pipeline: em_c = em[t], em_p1 = em[t+1] (in flight)
    float em_c  = embase[NKT + j];          // t = 1
    float em_p1 = embase[2 * NKT + j];      // t = 2

    for (int t = 1; t < NT; ++t) {
        const float em_p2 = (t + 2 < NT) ? embase[(size_t)(t + 2) * NKT + j] : 0.0f;

        // batched broadcast read of the 16 scores this half reduces over
        float4 s0 = *(const float4*)&score_s[h * 16];
        float4 s1 = *(const float4*)&score_s[h * 16 + 4];
        float4 s2 = *(const float4*)&score_s[h * 16 + 8];
        float4 s3 = *(const float4*)&score_s[h * 16 + 12];
        const float sc[16] = {s0.x, s0.y, s0.z, s0.w, s1.x, s1.y, s1.z, s1.w,
                              s2.x, s2.y, s2.z, s2.w, s3.x, s3.y, s3.z, s3.w};

        float v[16];
#pragma unroll
        for (int ii = 0; ii < 16; ++ii) {
            v[ii] = (sc[ii] + tr_reg[ii]) + em_c;  // np add order
        }
        // in-lane argmax tree, left (lower index) preferred on ties
        float l1v[8]; int l1i[8];
#pragma unroll
        for (int p = 0; p < 8; ++p) {
            const bool L = v[2 * p] >= v[2 * p + 1];
            l1v[p] = L ? v[2 * p] : v[2 * p + 1];
            l1i[p] = L ? 2 * p : 2 * p + 1;
        }
        float l2v[4]; int l2i[4];
#pragma unroll
        for (int p = 0; p < 4; ++p) {
            const bool L = l1v[2 * p] >= l1v[2 * p + 1];
            l2v[p] = L ? l1v[2 * p] : l1v[2 * p + 1];
            l2i[p] = L ? l1i[2 * p] : l1i[2 * p + 1];
        }
        float l3v[2]; int l3i[2];
#pragma unroll
        for (int p = 0; p < 2; ++p) {
            const bool L = l2v[2 * p] >= l2v[2 * p + 1];
            l3v[p] = L ? l2v[2 * p] : l2v[2 * p + 1];
            l3i[p] = L ? l2i[2 * p] : l2i[2 * p + 1];
        }
        const bool L4 = l3v[0] >= l3v[1];
        const float best = L4 ? l3v[0] : l3v[1];
        const int   bi   = h * 16 + (L4 ? l3i[0] : l3i[1]);

        // cross-half combine (ties -> low half -> smaller i)
        const float ob  = __shfl(best, lane ^ 32);
        const int   obi = __shfl(bi,   lane ^ 32);
        const bool take_other = h ? (ob >= best) : (ob > best);
        const float ns = take_other ? ob : best;
        const int  arg = take_other ? obi : bi;

        if (h == 0) {
            hist[(t - 1) * 32 + j] = (unsigned char)arg;
            score_s[j] = ns;
        }
        __syncthreads();

        em_c  = em_p1;
        em_p1 = em_p2;
    }

    // final argmax over j (first-index-wins butterfly)
    float fv = score_s[j] + et;
    int fi = j;
#pragma unroll
    for (int dlt = 1; dlt <= 16; dlt <<= 1) {
        const float vo = __shfl_xor(fv, dlt);
        const int   io = __shfl_xor(fi, dlt);
        if (vo > fv || (vo == fv && io < fi)) { fv = vo; fi = io; }
    }

    if (lane == 0) {
        int tag = fi;
        out[b * NT + (NT - 1)] = tag;
        for (int t = NT - 2; t >= 0; --t) {
            tag = hist[t * 32 + tag];
            out[b * NT + t] = tag;
        }
    }
}

// ---------------------------------------------------------------------------
extern "C" void kernel_launch(void* const* d_in, const int* in_sizes, int n_in,
                              void* d_out, int out_size, void* d_ws, size_t ws_size,
                              hipStream_t stream) {
    const int*   inputs  = (const int*)d_in[0];
    // d_in[1] = tags (unused by forward/decode)
    const float* emb     = (const float*)d_in[2];
    const float* w_ih_l0 = (const float*)d_in[3];
    const float* w_hh_l0 = (const float*)d_in[4];
    const float* b_l0    = (const float*)d_in[5];
    const float* w_ih_l1 = (const float*)d_in[6];
    const float* w_hh_l1 = (const float*)d_in[7];
    const float* b_l1    = (const float*)d_in[8];
    const float* W_out   = (const float*)d_in[9];
    const float* b_out   = (const float*)d_in[10];
    const float* start_t = (const float*)d_in[11];
    const float* end_t   = (const float*)d_in[12];
    const float* trans   = (const float*)d_in[13];
    int* out = (int*)d_out;

    float* ws  = (float*)d_ws;
    float* zin = ws;                                        // 2*B*CHUNK*512
    float* h1  = zin + (size_t)2 * NB * CHUNK * NG4;        // B*T*256
    float* h2  = h1 + (size_t)NB * NT * 256;                // B*T*256
    float* sth = h2 + (size_t)NB * NT * 256;                // 2*B*128
    float* stc = sth + (size_t)2 * NB * NH;                 // 2*B*128
    float* em  = stc + (size_t)2 * NB * NH;                 // B*T*32

    // Layer 0: chunked input-projection GEMM + recurrence
    for (int c = 0; c < NCH; ++c) {
        proj_gemm16x8<128><<<512, 256, 0, stream>>>(w_ih_l0, b_l0, emb, inputs, zin, c);
        lstm_rec512<<<256, 512, 0, stream>>>(w_hh_l0, zin, h1, sth, stc, c);
    }
    // Layer 1
    for (int c = 0; c < NCH; ++c) {
        proj_gemm16x8<256><<<512, 256, 0, stream>>>(w_ih_l1, b_l1, h1, nullptr, zin, c);
        lstm_rec512<<<256, 512, 0, stream>>>(w_hh_l1, zin, h2, sth, stc, c);
    }
    // Emissions + Viterbi decode
    emis_kernel<<<(NB * NT) / 64, 256, 0, stream>>>(h2, W_out, b_out, em);
    viterbi_v3<<<NB, 64, 0, stream>>>(em, start_t, end_t, trans, out);
}